// Round 2
// baseline (216.063 us; speedup 1.0000x reference)
//
#include <hip/hip_runtime.h>

// SSIM 3D, round 2: separable rank-1 window (u ⊗ v ⊗ t), fused W->H->D.
// W-conv taps read global directly (L1-served), H-exchange via small
// double-buffered LDS (float4+float, ds_read_b128), D-conv in a fully
// static register ring (5-phase unrolled). 1 barrier per depth slice.

#define NDIM 128
#define TW 16      // output tile W
#define TH 12      // output tile H (W-conv grid is 16 rows = TH+4)
#define DSUB 32
#define NWT 8
#define NHT 11     // ceil(128/12)
#define NDT 4
#define NB  4
#define NBLK (NWT*NHT*NDT*NB)   // 1408

__global__ void factorize_window(const float* __restrict__ w, float* __restrict__ ws) {
    if (threadIdx.x == 0) {
        float w000 = w[0];
        #pragma unroll
        for (int i = 0; i < 5; ++i) ws[i]      = w[i * 25];
        #pragma unroll
        for (int j = 0; j < 5; ++j) ws[5 + j]  = w[j * 5] / w000;
        #pragma unroll
        for (int k = 0; k < 5; ++k) ws[10 + k] = w[k] / w000;
    }
}

__launch_bounds__(256, 4)
__global__ void ssim_main(const float* __restrict__ img1,
                          const float* __restrict__ img2,
                          const float* __restrict__ wfac,
                          float* __restrict__ partials) {
    const int bid = blockIdx.x;
    const int tw = bid % NWT;
    int t1 = bid / NWT;
    const int th = t1 % NHT; t1 /= NHT;
    const int td = t1 % NDT;
    const int b  = t1 / NDT;

    const int w0 = tw * TW, h0 = th * TH, d0 = td * DSUB;
    const float* __restrict__ x1 = img1 + (size_t)(b * 2 + 1) * NDIM * NDIM * NDIM;
    const float* __restrict__ x2 = img2 + (size_t)b * NDIM * NDIM * NDIM;

    float uW[5], vW[5], tW[5];
    #pragma unroll
    for (int i = 0; i < 5; ++i) { uW[i] = wfac[i]; vW[i] = wfac[5 + i]; tW[i] = wfac[10 + i]; }

    __shared__ float4 sWc4[2][256];   // fields m1,m2,q11,q22
    __shared__ float  sWc1[2][256];   // field q12
    __shared__ float  sRed[4];

    const int tid = threadIdx.x;
    const int wc  = tid & 15;         // col within tile
    const int rr  = tid >> 4;         // W-conv row 0..15  (gh = h0+rr-2)
    const int gw  = w0 + wc;
    const int ghw = h0 + rr - 2;
    const bool outOK = (rr < TH) && ((h0 + rr) < NDIM);

    float ring[5][5];                 // [slot][field], all static indices
    float accS = 0.f;

#define PHASE(I, P) do {                                                      \
    const int i_ = (I);                                                       \
    const int d_ = d0 - 2 + i_;                                               \
    float m1_=0.f, m2_=0.f, q11_=0.f, q22_=0.f, q12_=0.f;                     \
    if (((unsigned)d_ < NDIM) && ((unsigned)ghw < NDIM)) {                    \
        const float* __restrict__ r1_ = x1 + ((size_t)d_ * NDIM + ghw) * NDIM;\
        const float* __restrict__ r2_ = x2 + ((size_t)d_ * NDIM + ghw) * NDIM;\
        _Pragma("unroll")                                                     \
        for (int c_ = 0; c_ < 5; ++c_) {                                      \
            const int g_ = gw + c_ - 2;                                       \
            if ((unsigned)g_ < NDIM) {                                        \
                const float a_ = r1_[g_], bb_ = r2_[g_];                      \
                const float ta_ = tW[c_] * a_, tb_ = tW[c_] * bb_;            \
                m1_ += ta_; m2_ += tb_;                                       \
                q11_ += ta_ * a_; q22_ += tb_ * bb_; q12_ += ta_ * bb_;       \
            }                                                                 \
        }                                                                     \
    }                                                                         \
    {                                                                         \
        const int buf_ = i_ & 1;                                              \
        sWc4[buf_][tid] = make_float4(m1_, m2_, q11_, q22_);                  \
        sWc1[buf_][tid] = q12_;                                               \
        __syncthreads();                                                      \
        if (rr < TH) {                                                        \
            float h0_=0.f, h1_=0.f, h2_=0.f, h3_=0.f, h4_=0.f;                \
            _Pragma("unroll")                                                 \
            for (int r_ = 0; r_ < 5; ++r_) {                                  \
                const int ix_ = (rr + r_) * 16 + wc;                          \
                const float4 f4_ = sWc4[buf_][ix_];                           \
                const float  f1_ = sWc1[buf_][ix_];                           \
                const float  vw_ = vW[r_];                                    \
                h0_ += vw_ * f4_.x; h1_ += vw_ * f4_.y; h2_ += vw_ * f4_.z;   \
                h3_ += vw_ * f4_.w; h4_ += vw_ * f1_;                         \
            }                                                                 \
            ring[(P)][0] = h0_; ring[(P)][1] = h1_; ring[(P)][2] = h2_;       \
            ring[(P)][3] = h3_; ring[(P)][4] = h4_;                           \
            if (i_ >= 4 && outOK) {                                           \
                float F0=0.f, F1=0.f, F2=0.f, F3=0.f, F4=0.f;                 \
                _Pragma("unroll")                                             \
                for (int j_ = 0; j_ < 5; ++j_) {                              \
                    const int s_ = ((P) + 1 + j_) % 5;                        \
                    const float uw_ = uW[j_];                                 \
                    F0 += uw_ * ring[s_][0]; F1 += uw_ * ring[s_][1];         \
                    F2 += uw_ * ring[s_][2]; F3 += uw_ * ring[s_][3];         \
                    F4 += uw_ * ring[s_][4];                                  \
                }                                                             \
                const float mu1 = F0, mu2 = F1;                               \
                const float mu1sq = mu1*mu1, mu2sq = mu2*mu2, mu12 = mu1*mu2; \
                const float s11 = F2 - mu1sq, s22 = F3 - mu2sq;               \
                const float s12 = F4 - mu12;                                  \
                const float num = (2.f*mu12 + 1e-4f) * (2.f*s12 + 9e-4f);     \
                const float den = (mu1sq + mu2sq + 1e-4f) * (s11 + s22 + 9e-4f);\
                accS += __fdividef(num, den);                                 \
            }                                                                 \
        }                                                                     \
    }                                                                         \
} while (0)

    // 36 slices: d0-2 .. d0+33.  7 groups of 5 + 1 epilogue (35 % 5 == 0).
    for (int io = 0; io < 7; ++io) {
        const int ib = io * 5;
        PHASE(ib + 0, 0);
        PHASE(ib + 1, 1);
        PHASE(ib + 2, 2);
        PHASE(ib + 3, 3);
        PHASE(ib + 4, 4);
    }
    PHASE(35, 0);
#undef PHASE

    // block reduction
    #pragma unroll
    for (int off = 32; off > 0; off >>= 1)
        accS += __shfl_down(accS, off, 64);
    __syncthreads();
    if ((tid & 63) == 0) sRed[tid >> 6] = accS;
    __syncthreads();
    if (tid == 0) partials[bid] = sRed[0] + sRed[1] + sRed[2] + sRed[3];
}

__global__ void finalize_kernel(const float* __restrict__ partials, float* __restrict__ out) {
    const int tid = threadIdx.x;
    double s = 0.0;
    for (int i = tid; i < NBLK; i += 256) s += (double)partials[i];
    #pragma unroll
    for (int off = 32; off > 0; off >>= 1)
        s += __shfl_down(s, off, 64);
    __shared__ double sm[4];
    if ((tid & 63) == 0) sm[tid >> 6] = s;
    __syncthreads();
    if (tid == 0)
        out[0] = 1.0f - (float)((sm[0] + sm[1] + sm[2] + sm[3]) / (double)(4LL * 128 * 128 * 128));
}

extern "C" void kernel_launch(void* const* d_in, const int* in_sizes, int n_in,
                              void* d_out, int out_size, void* d_ws, size_t ws_size,
                              hipStream_t stream) {
    const float* img1 = (const float*)d_in[0];   // (4,2,128,128,128) fp32
    const float* img2 = (const float*)d_in[1];   // (4,1,128,128,128) fp32
    const float* win  = (const float*)d_in[2];   // (1,1,5,5,5) fp32
    float* out = (float*)d_out;
    float* ws  = (float*)d_ws;
    float* wfac     = ws;         // 16 floats
    float* partials = ws + 16;    // NBLK floats, fully rewritten every launch

    hipLaunchKernelGGL(factorize_window, dim3(1), dim3(64), 0, stream, win, wfac);
    hipLaunchKernelGGL(ssim_main, dim3(NBLK), dim3(256), 0, stream, img1, img2, wfac, partials);
    hipLaunchKernelGGL(finalize_kernel, dim3(1), dim3(256), 0, stream, partials, out);
}

// Round 3
// 162.773 us; speedup vs baseline: 1.3274x; 1.3274x over previous
//
#include <hip/hip_runtime.h>

// SSIM 3D, round 3. Separable rank-1 window (u ⊗ v ⊗ t), fused W->H->D.
// - W-conv: aligned float4 global loads (coalesced, L1-friendly) -> registers,
//   5 fields x 4 cols per thread.
// - Single LDS exchange per slice for the H transpose: float4 writes,
//   float2 reads, conflict-free, 2 barriers/slice.
// - D-conv: static register ring (5 slots x 5 fields x float2), 5-phase unroll.
// Tile: W=128 (full row), TH=4 output rows, DSUB=16 depth -> 1024 blocks.

#define NDIM 128
#define TH 4
#define WR (TH + 4)            // 8 W-conv rows
#define DSUB 16
#define NHT (NDIM / TH)        // 32
#define NDT (NDIM / DSUB)      // 8
#define NB 4
#define NBLK (NHT * NDT * NB)  // 1024

__global__ void factorize_window(const float* __restrict__ w, float* __restrict__ ws) {
    if (threadIdx.x == 0) {
        float w000 = w[0];
        #pragma unroll
        for (int i = 0; i < 5; ++i) ws[i]      = w[i * 25];
        #pragma unroll
        for (int j = 0; j < 5; ++j) ws[5 + j]  = w[j * 5] / w000;
        #pragma unroll
        for (int k = 0; k < 5; ++k) ws[10 + k] = w[k] / w000;
    }
}

__launch_bounds__(256, 4)
__global__ void ssim_main(const float* __restrict__ img1,
                          const float* __restrict__ img2,
                          const float* __restrict__ wfac,
                          float* __restrict__ partials) {
    const int bid = blockIdx.x;
    const int th = bid % NHT;
    const int td = (bid / NHT) % NDT;
    const int b  = bid / (NHT * NDT);

    const int h0 = th * TH, d0 = td * DSUB;
    const float* __restrict__ x1 = img1 + (size_t)(b * 2 + 1) * NDIM * NDIM * NDIM;
    const float* __restrict__ x2 = img2 + (size_t)b * NDIM * NDIM * NDIM;

    float uW[5], vW[5], tW[5];
    #pragma unroll
    for (int i = 0; i < 5; ++i) { uW[i] = wfac[i]; vW[i] = wfac[5 + i]; tW[i] = wfac[10 + i]; }

    __shared__ float sWc[5][WR][NDIM];   // 20 KB
    __shared__ float sRed[4];

    const int tid  = threadIdx.x;
    // W-conv mapping: 8 rows x 32 col-groups of 4
    const int wrow = tid >> 5;
    const int wcg  = tid & 31;
    const int c0   = wcg * 4;
    const int ghw  = h0 + wrow - 2;
    // H/D mapping: 4 rows x 64 col-pairs of 2
    const int orow = tid >> 6;
    const int oc   = (tid & 63) * 2;

    float2 ring[5][5];                   // [slot][field], static indices only
    float2 accS = make_float2(0.f, 0.f);

#define PHASE(I, P) do {                                                       \
    const int i_ = (I);                                                        \
    const int d_ = d0 - 2 + i_;                                                \
    float4 A0 = make_float4(0,0,0,0), A1 = A0, A2 = A0;                        \
    float4 B0 = A0, B1 = A0, B2 = A0;                                          \
    if (((unsigned)d_ < NDIM) && ((unsigned)ghw < NDIM)) {                     \
        const float* __restrict__ r1_ = x1 + ((size_t)d_ * NDIM + ghw) * NDIM; \
        const float* __restrict__ r2_ = x2 + ((size_t)d_ * NDIM + ghw) * NDIM; \
        if (wcg > 0)  { A0 = *(const float4*)(r1_ + c0 - 4);                   \
                        B0 = *(const float4*)(r2_ + c0 - 4); }                 \
        A1 = *(const float4*)(r1_ + c0);                                       \
        B1 = *(const float4*)(r2_ + c0);                                       \
        if (wcg < 31) { A2 = *(const float4*)(r1_ + c0 + 4);                   \
                        B2 = *(const float4*)(r2_ + c0 + 4); }                 \
    }                                                                          \
    float ra[12] = {A0.x,A0.y,A0.z,A0.w, A1.x,A1.y,A1.z,A1.w,                  \
                    A2.x,A2.y,A2.z,A2.w};                                      \
    float rb[12] = {B0.x,B0.y,B0.z,B0.w, B1.x,B1.y,B1.z,B1.w,                  \
                    B2.x,B2.y,B2.z,B2.w};                                      \
    float m1v[4], m2v[4], q11v[4], q22v[4], q12v[4];                           \
    _Pragma("unroll")                                                          \
    for (int k_ = 0; k_ < 4; ++k_) {                                           \
        float m1_=0.f, m2_=0.f, q11_=0.f, q22_=0.f, q12_=0.f;                  \
        _Pragma("unroll")                                                      \
        for (int c_ = 0; c_ < 5; ++c_) {                                       \
            const float a_ = ra[k_ + c_ + 2], b_ = rb[k_ + c_ + 2];            \
            const float ta_ = tW[c_] * a_, tb_ = tW[c_] * b_;                  \
            m1_ += ta_; m2_ += tb_;                                            \
            q11_ += ta_ * a_; q22_ += tb_ * b_; q12_ += ta_ * b_;              \
        }                                                                      \
        m1v[k_]=m1_; m2v[k_]=m2_; q11v[k_]=q11_; q22v[k_]=q22_; q12v[k_]=q12_; \
    }                                                                          \
    __syncthreads();   /* prev phase's reads of sWc complete */                \
    *(float4*)&sWc[0][wrow][c0] = make_float4(m1v[0],m1v[1],m1v[2],m1v[3]);    \
    *(float4*)&sWc[1][wrow][c0] = make_float4(m2v[0],m2v[1],m2v[2],m2v[3]);    \
    *(float4*)&sWc[2][wrow][c0] = make_float4(q11v[0],q11v[1],q11v[2],q11v[3]);\
    *(float4*)&sWc[3][wrow][c0] = make_float4(q22v[0],q22v[1],q22v[2],q22v[3]);\
    *(float4*)&sWc[4][wrow][c0] = make_float4(q12v[0],q12v[1],q12v[2],q12v[3]);\
    __syncthreads();   /* writes visible */                                    \
    _Pragma("unroll")                                                          \
    for (int f_ = 0; f_ < 5; ++f_) {                                           \
        float2 F_ = make_float2(0.f, 0.f);                                     \
        _Pragma("unroll")                                                      \
        for (int r_ = 0; r_ < 5; ++r_) {                                       \
            const float2 wv_ = *(const float2*)&sWc[f_][orow + r_][oc];        \
            F_.x += vW[r_] * wv_.x;                                            \
            F_.y += vW[r_] * wv_.y;                                            \
        }                                                                      \
        ring[(P)][f_] = F_;                                                    \
    }                                                                          \
    if (i_ >= 4) {                                                             \
        float2 F0 = make_float2(0,0), F1 = F0, F2 = F0, F3 = F0, F4 = F0;      \
        _Pragma("unroll")                                                      \
        for (int j_ = 0; j_ < 5; ++j_) {                                       \
            const int s_ = ((P) + 1 + j_) % 5;                                 \
            const float uw_ = uW[j_];                                          \
            F0.x += uw_*ring[s_][0].x; F0.y += uw_*ring[s_][0].y;              \
            F1.x += uw_*ring[s_][1].x; F1.y += uw_*ring[s_][1].y;              \
            F2.x += uw_*ring[s_][2].x; F2.y += uw_*ring[s_][2].y;              \
            F3.x += uw_*ring[s_][3].x; F3.y += uw_*ring[s_][3].y;              \
            F4.x += uw_*ring[s_][4].x; F4.y += uw_*ring[s_][4].y;              \
        }                                                                      \
        {                                                                      \
            const float mu1 = F0.x, mu2 = F1.x;                                \
            const float m11 = mu1*mu1, m22 = mu2*mu2, m12 = mu1*mu2;           \
            const float num = (2.f*m12 + 1e-4f) * (2.f*(F4.x - m12) + 9e-4f);  \
            const float den = (m11 + m22 + 1e-4f) *                            \
                              ((F2.x - m11) + (F3.x - m22) + 9e-4f);           \
            accS.x += __fdividef(num, den);                                    \
        }                                                                      \
        {                                                                      \
            const float mu1 = F0.y, mu2 = F1.y;                                \
            const float m11 = mu1*mu1, m22 = mu2*mu2, m12 = mu1*mu2;           \
            const float num = (2.f*m12 + 1e-4f) * (2.f*(F4.y - m12) + 9e-4f);  \
            const float den = (m11 + m22 + 1e-4f) *                            \
                              ((F2.y - m11) + (F3.y - m22) + 9e-4f);           \
            accS.y += __fdividef(num, den);                                    \
        }                                                                      \
    }                                                                          \
} while (0)

    // 20 slices: d0-2 .. d0+17, 4 groups of 5 phases
    for (int io = 0; io < 4; ++io) {
        const int ib = io * 5;
        PHASE(ib + 0, 0);
        PHASE(ib + 1, 1);
        PHASE(ib + 2, 2);
        PHASE(ib + 3, 3);
        PHASE(ib + 4, 4);
    }
#undef PHASE

    float acc = accS.x + accS.y;
    #pragma unroll
    for (int off = 32; off > 0; off >>= 1)
        acc += __shfl_down(acc, off, 64);
    __syncthreads();
    if ((tid & 63) == 0) sRed[tid >> 6] = acc;
    __syncthreads();
    if (tid == 0) partials[bid] = sRed[0] + sRed[1] + sRed[2] + sRed[3];
}

__global__ void finalize_kernel(const float* __restrict__ partials, float* __restrict__ out) {
    const int tid = threadIdx.x;
    double s = 0.0;
    for (int i = tid; i < NBLK; i += 256) s += (double)partials[i];
    #pragma unroll
    for (int off = 32; off > 0; off >>= 1)
        s += __shfl_down(s, off, 64);
    __shared__ double sm[4];
    if ((tid & 63) == 0) sm[tid >> 6] = s;
    __syncthreads();
    if (tid == 0)
        out[0] = 1.0f - (float)((sm[0] + sm[1] + sm[2] + sm[3]) / (double)(4LL * 128 * 128 * 128));
}

extern "C" void kernel_launch(void* const* d_in, const int* in_sizes, int n_in,
                              void* d_out, int out_size, void* d_ws, size_t ws_size,
                              hipStream_t stream) {
    const float* img1 = (const float*)d_in[0];   // (4,2,128,128,128) fp32
    const float* img2 = (const float*)d_in[1];   // (4,1,128,128,128) fp32
    const float* win  = (const float*)d_in[2];   // (1,1,5,5,5) fp32
    float* out = (float*)d_out;
    float* ws  = (float*)d_ws;
    float* wfac     = ws;         // 16 floats
    float* partials = ws + 16;    // NBLK floats, fully rewritten every launch

    hipLaunchKernelGGL(factorize_window, dim3(1), dim3(64), 0, stream, win, wfac);
    hipLaunchKernelGGL(ssim_main, dim3(NBLK), dim3(256), 0, stream, img1, img2, wfac, partials);
    hipLaunchKernelGGL(finalize_kernel, dim3(1), dim3(256), 0, stream, partials, out);
}